// Round 8
// baseline (268.006 us; speedup 1.0000x reference)
//
#include <hip/hip_runtime.h>
#include <hip/hip_bf16.h>
#include <stdint.h>

#define VOCAB 50257
#define WD 300
#define KP1 320              // word dim padded to mult of 32
#define MP 50432             // vocab rows padded: 394*128

using bf16 = __hip_bfloat16;
typedef __attribute__((ext_vector_type(4))) float f32x4;
typedef __attribute__((ext_vector_type(8))) short bf16x8;

// async global->LDS, 16B per lane; LDS dest = wave-uniform base + lane*16
__device__ __forceinline__ void async_load16(const void* g, void* l) {
    __builtin_amdgcn_global_load_lds(
        (const __attribute__((address_space(1))) uint32_t*)(uintptr_t)g,
        (__attribute__((address_space(3))) uint32_t*)l, 16, 0, 0);
}

// ---------- prep: w1t = W1^T bf16 [256x320]; w2t = W2^T bf16 [256x512];
//                  w2b = W2 cast bf16 [512x256]; b4 = b2@(A+B)+b2; zbuf zeros
__global__ void prep_w(const float* __restrict__ W1, const float* __restrict__ W2,
                       const float* __restrict__ b2,
                       bf16* __restrict__ w1t, bf16* __restrict__ w2t,
                       bf16* __restrict__ w2b, float* __restrict__ b4,
                       float* __restrict__ zbuf) {
    if (blockIdx.x == 1344) {           // bias block: b4 = b2@(A+B) + b2
        __shared__ float b2s[256];
        int n = threadIdx.x;
        b2s[n] = b2[n];
        __syncthreads();
        float acc = b2s[n];
        #pragma unroll 8
        for (int k = 0; k < 256; ++k)
            acc += b2s[k] * (W2[k * 256 + n] + W2[(k + 256) * 256 + n]);
        b4[n] = acc;
        if (n < 16) zbuf[n] = 0.0f;
        return;
    }
    int idx = blockIdx.x * 256 + threadIdx.x;
    if (idx < 256 * KP1) {                              // w1t
        int n = idx / KP1;
        int k = idx - n * KP1;
        w1t[idx] = __float2bfloat16(k < WD ? W1[k * 256 + n] : 0.0f);
    } else if (idx < 256 * KP1 + 131072) {              // w2t
        int j = idx - 256 * KP1;
        int n = j >> 9, k = j & 511;
        w2t[j] = __float2bfloat16(W2[k * 256 + n]);
    } else {                                            // w2b: plain cast
        int j = idx - 256 * KP1 - 131072;
        w2b[j] = __float2bfloat16(W2[j]);
    }
}

// ---------- gemm128: 128x128 tile, 4 waves, m97 2-barrier (W4T only) ---------
// AMODE 3: W4 products: grid.z = j; A-op = w2t + 256*(j>>1), BT = w2b + 65536*(j&1)
template <int AMODE, bool OUT_F32>
__global__ __launch_bounds__(256)
void gemm128(const void* __restrict__ Av, const bf16* __restrict__ BT,
             const float* __restrict__ bias, void* __restrict__ C,
             int M, int K, int As, int Bstr, int Cs) {
    __shared__ char smem[8192 + 8192];
    char* Asm = smem;
    bf16* Bsm = (bf16*)(smem + 8192);

    const int t = threadIdx.x, w = t >> 6, lane = t & 63;
    const int wr = w >> 1, wc = w & 1, mi = lane & 15, q = lane >> 4;
    const int m0 = blockIdx.x * 128, n0 = blockIdx.y * 128;

    const bf16* Ab = (const bf16*)Av;
    const bf16* BTp = BT;
    int coff = 0;
    if constexpr (AMODE == 3) {
        int j = blockIdx.z;
        Ab = (const bf16*)Av + 256 * (j >> 1);
        BTp = BT + 65536 * (j & 1);
        coff = 256 * j;
    }

    f32x4 acc[4][4] = {};

    for (int k0 = 0; k0 < K; k0 += 32) {
        #pragma unroll
        for (int i = 0; i < 2; ++i) {
            int s = i * 256 + t;
            int row = s >> 2;
            int kcd = (s & 3) ^ ((row >> 2) & 3);
            async_load16(Ab + (size_t)(m0 + row) * As + k0 + kcd * 8,
                         Asm + i * 4096 + w * 1024);
        }
        #pragma unroll
        for (int i = 0; i < 2; ++i) {
            int s = i * 256 + t;
            int col = s >> 2;
            int kcd = (s & 3) ^ ((col >> 2) & 3);
            async_load16(BTp + (size_t)(n0 + col) * Bstr + k0 + kcd * 8,
                         (char*)Bsm + i * 4096 + w * 1024);
        }
        __syncthreads();

        bf16x8 af[4], bfr[4];
        const bf16* As16 = (const bf16*)Asm;
        #pragma unroll
        for (int r = 0; r < 4; ++r) {
            int row = wr * 64 + r * 16 + mi;
            int slot = row * 4 + (q ^ ((row >> 2) & 3));
            af[r] = *(const bf16x8*)(As16 + slot * 8);
        }
        #pragma unroll
        for (int c = 0; c < 4; ++c) {
            int col = wc * 64 + c * 16 + mi;
            int slot = col * 4 + (q ^ ((col >> 2) & 3));
            bfr[c] = *(const bf16x8*)(Bsm + slot * 8);
        }
        #pragma unroll
        for (int r = 0; r < 4; ++r)
            #pragma unroll
            for (int c = 0; c < 4; ++c)
                acc[r][c] = __builtin_amdgcn_mfma_f32_16x16x32_bf16(af[r], bfr[c], acc[r][c], 0, 0, 0);
        __syncthreads();
    }

    #pragma unroll
    for (int r = 0; r < 4; ++r) {
        int rowb = m0 + wr * 64 + r * 16 + q * 4;
        #pragma unroll
        for (int c = 0; c < 4; ++c) {
            int col = n0 + wc * 64 + c * 16 + mi;
            float bv = (AMODE == 3) ? 0.0f : bias[col];
            #pragma unroll
            for (int i = 0; i < 4; ++i) {
                float v = acc[r][c][i] + bv;
                size_t o = (size_t)(rowb + i) * Cs + coff + col;
                if (OUT_F32) ((float*)C)[o] = v;
                else         ((bf16*)C)[o] = __float2bfloat16(v);
            }
        }
    }
}

// ---------- gemm512: 128-row x FULL-256-col tile, 8 waves (2 rg x 4 cg) ------
// AMODE 0: A bf16 [M x K] contiguous
// AMODE 1: A row r = concat4(proj[ids4[m0+r]]), K = 1024 (fused leaf gather)
// AMODE 2: A fp32 emb rows (stride WD, rows clamped to VOCAB-1), K = KP1
// PIPE: 3-stage LDS pipeline, fine vmcnt — use when blocks/CU <= 2 anyway.
template <int AMODE, bool PIPE, bool OUT_F32>
__global__ __launch_bounds__(512)
void gemm512(const void* __restrict__ Av, const int* __restrict__ ids,
             const bf16* __restrict__ BT, const float* __restrict__ bias,
             void* __restrict__ C, int K, const float* __restrict__ zbuf) {
    constexpr int ASZ = (AMODE == 2) ? 16384 : 8192;
    constexpr int BSZ = 16384, STAGE = ASZ + BSZ;
    __shared__ char smem[PIPE ? 3 * STAGE : STAGE];

    const int t = threadIdx.x, w = t >> 6, lane = t & 63;
    const int rg = w >> 2, cg = w & 3, mi = lane & 15, q = lane >> 4;
    const int m0 = blockIdx.x * 128;
    const bf16* Ab = (const bf16*)Av;

    int4 idq = {0, 0, 0, 0};
    if constexpr (AMODE == 1) idq = ((const int4*)ids)[m0 + (t >> 2)];

    auto stage = [&](int ke, int buf) {
        char* Asm = smem + buf * STAGE;
        char* Bsm = Asm + ASZ;
        if constexpr (AMODE == 2) {
            const float* A32 = (const float*)Av;
            #pragma unroll
            for (int i = 0; i < 2; ++i) {               // 1024 fp32x4 chunks
                int s = i * 512 + t;
                int row = s >> 3;
                int kcd = (s & 7) ^ (row & 7);
                int k = ke + kcd * 4;
                int grow = m0 + row; if (grow >= VOCAB) grow = VOCAB - 1;
                const float* g = (k <= 296) ? (A32 + (size_t)grow * WD + k) : zbuf;
                async_load16(g, Asm + i * 8192 + w * 1024);
            }
        } else {
            int row = t >> 2;                           // 512 bf16x8 chunks, 1/thread
            int kcd = (t & 3) ^ ((row >> 2) & 3);
            const bf16* g;
            if constexpr (AMODE == 1) {
                int sel = ke >> 8;                      // leaf slot, wave-uniform
                int id = (sel & 2) ? ((sel & 1) ? idq.w : idq.z)
                                   : ((sel & 1) ? idq.y : idq.x);
                g = Ab + (size_t)id * 256 + (ke & 255) + kcd * 8;
            } else {
                g = Ab + (size_t)(m0 + row) * K + ke + kcd * 8;
            }
            async_load16(g, Asm + w * 1024);
        }
        #pragma unroll
        for (int i = 0; i < 2; ++i) {                   // B: 1024 chunks, 2/thread
            int s = i * 512 + t;
            int col = s >> 2;
            int kcd = (s & 3) ^ ((col >> 2) & 3);
            async_load16(BT + (size_t)col * K + ke + kcd * 8,
                         Bsm + i * 8192 + w * 1024);
        }
    };

    f32x4 acc[4][4] = {};

    auto compute = [&](int buf) {
        const char* Asm = smem + buf * STAGE;
        const bf16* Bs16 = (const bf16*)(Asm + ASZ);
        bf16x8 af[4], bfr[4];
        if constexpr (AMODE == 2) {
            const float* As32 = (const float*)Asm;
            #pragma unroll
            for (int r = 0; r < 4; ++r) {
                int row = rg * 64 + r * 16 + mi;
                int sl = row * 8 + ((2 * q) ^ (row & 7));
                f32x4 lo = *(const f32x4*)(As32 + sl * 4);
                f32x4 hi = *(const f32x4*)(As32 + (sl ^ 1) * 4);
                union { bf16x8 v; bf16 h[8]; } u;
                #pragma unroll
                for (int j = 0; j < 4; ++j) u.h[j] = __float2bfloat16(lo[j]);
                #pragma unroll
                for (int j = 0; j < 4; ++j) u.h[4 + j] = __float2bfloat16(hi[j]);
                af[r] = u.v;
            }
        } else {
            const bf16* As16 = (const bf16*)Asm;
            #pragma unroll
            for (int r = 0; r < 4; ++r) {
                int row = rg * 64 + r * 16 + mi;
                int slot = row * 4 + (q ^ ((row >> 2) & 3));
                af[r] = *(const bf16x8*)(As16 + slot * 8);
            }
        }
        #pragma unroll
        for (int c = 0; c < 4; ++c) {
            int col = cg * 64 + c * 16 + mi;
            int slot = col * 4 + (q ^ ((col >> 2) & 3));
            bfr[c] = *(const bf16x8*)(Bs16 + slot * 8);
        }
        #pragma unroll
        for (int r = 0; r < 4; ++r)
            #pragma unroll
            for (int c = 0; c < 4; ++c)
                acc[r][c] = __builtin_amdgcn_mfma_f32_16x16x32_bf16(af[r], bfr[c], acc[r][c], 0, 0, 0);
    };

    const int S = K >> 5;
    if constexpr (!PIPE) {
        for (int k0 = 0; k0 < S; ++k0) {
            stage(k0 * 32, 0);
            __syncthreads();
            compute(0);
            __syncthreads();
        }
    } else {
        stage(0, 0);
        if (S > 1) stage(32, 1);
        for (int k0 = 0; k0 < S; ++k0) {
            if (k0 + 1 < S) {
                if constexpr (AMODE == 2)
                    asm volatile("s_waitcnt vmcnt(4)\n\ts_barrier" ::: "memory");
                else
                    asm volatile("s_waitcnt vmcnt(3)\n\ts_barrier" ::: "memory");
            } else {
                asm volatile("s_waitcnt vmcnt(0)\n\ts_barrier" ::: "memory");
            }
            if (k0 + 2 < S) stage((k0 + 2) * 32, (k0 + 2) % 3);
            compute(k0 % 3);
        }
    }

    // epilogue: C/D layout col = lane&15, row = (lane>>4)*4 + i
    #pragma unroll
    for (int r = 0; r < 4; ++r) {
        int rowb = m0 + rg * 64 + r * 16 + q * 4;
        #pragma unroll
        for (int c = 0; c < 4; ++c) {
            int col = cg * 64 + c * 16 + mi;
            float bv = bias[col];
            #pragma unroll
            for (int i = 0; i < 4; ++i) {
                float v = acc[r][c][i] + bv;
                size_t o = (size_t)(rowb + i) * 256 + col;
                if (OUT_F32) ((float*)C)[o] = v;
                else         ((bf16*)C)[o] = __float2bfloat16(v);
            }
        }
    }
}

// ---------- tail23: levels 8 and 9 fused, grid 8 ----------------------------
// Phase 1: M=1024 level (input t2 [1024 x 1024], 128 rows/block, PIPE),
//          epilogue to LDS Ht in phase-2 A-frag layout (+b4).
// Phase 2: M=256 level: A = Ht viewed [32 x 1024], B re-staged (B-only PIPE),
//          fp32 roots out[32*blk + r].
__global__ __launch_bounds__(512)
void tail23(const bf16* __restrict__ Hin, const bf16* __restrict__ BT,
            const float* __restrict__ b4, float* __restrict__ out) {
    constexpr int ASZ = 8192, BSZ = 16384, STAGE = ASZ + BSZ;
    __shared__ char smem[3 * STAGE];
    __shared__ bf16 Ht[32 * 1024];   // 64 KB: [kt 0..31][m 0..31][32 k-elems, quad-swizzled]

    const int t = threadIdx.x, w = t >> 6, lane = t & 63;
    const int rg = w >> 2, cg = w & 3, mi = lane & 15, q = lane >> 4;
    const int m0 = blockIdx.x * 128;

    // ---- phase 1: standard PIPE K-loop (A + B staged) ----
    auto stage1 = [&](int ke, int buf) {
        char* Asm = smem + buf * STAGE;
        char* Bsm = Asm + ASZ;
        int row = t >> 2;
        int kcd = (t & 3) ^ ((row >> 2) & 3);
        async_load16(Hin + (size_t)(m0 + row) * 1024 + ke + kcd * 8, Asm + w * 1024);
        #pragma unroll
        for (int i = 0; i < 2; ++i) {
            int s = i * 512 + t;
            int col = s >> 2;
            int kcd2 = (s & 3) ^ ((col >> 2) & 3);
            async_load16(BT + (size_t)col * 1024 + ke + kcd2 * 8, Bsm + i * 8192 + w * 1024);
        }
    };

    f32x4 acc[4][4] = {};
    stage1(0, 0);
    stage1(32, 1);
    for (int k0 = 0; k0 < 32; ++k0) {
        if (k0 + 1 < 32)
            asm volatile("s_waitcnt vmcnt(3)\n\ts_barrier" ::: "memory");
        else
            asm volatile("s_waitcnt vmcnt(0)\n\ts_barrier" ::: "memory");
        if (k0 + 2 < 32) stage1((k0 + 2) * 32, (k0 + 2) % 3);
        const bf16* As16 = (const bf16*)(smem + (k0 % 3) * STAGE);
        const bf16* Bs16 = (const bf16*)(smem + (k0 % 3) * STAGE + ASZ);
        bf16x8 af[4], bfr[4];
        #pragma unroll
        for (int r = 0; r < 4; ++r) {
            int row = rg * 64 + r * 16 + mi;
            int slot = row * 4 + (q ^ ((row >> 2) & 3));
            af[r] = *(const bf16x8*)(As16 + slot * 8);
        }
        #pragma unroll
        for (int c = 0; c < 4; ++c) {
            int col = cg * 64 + c * 16 + mi;
            int slot = col * 4 + (q ^ ((col >> 2) & 3));
            bfr[c] = *(const bf16x8*)(Bs16 + slot * 8);
        }
        #pragma unroll
        for (int r = 0; r < 4; ++r)
            #pragma unroll
            for (int c = 0; c < 4; ++c)
                acc[r][c] = __builtin_amdgcn_mfma_f32_16x16x32_bf16(af[r], bfr[c], acc[r][c], 0, 0, 0);
    }

    // phase-1 epilogue -> Ht (+bias). t3 row r_out (0..127), col (0..255):
    // phase-2 m = r_out>>2, k = (r_out&3)*256 + col; kt = k>>5; chunk = (col>>3)&3
    // slot addr = (kt*32 + m)*32 + ((chunk ^ (m&3))*8) + (col&7)
    #pragma unroll
    for (int r = 0; r < 4; ++r) {
        int rowb = rg * 64 + r * 16 + q * 4;
        #pragma unroll
        for (int c = 0; c < 4; ++c) {
            int col = cg * 64 + c * 16 + mi;
            float bv = b4[col];
            int chunk = (col >> 3) & 3;
            #pragma unroll
            for (int i = 0; i < 4; ++i) {
                int r_out = rowb + i;
                int m = r_out >> 2;
                int kt = (r_out & 3) * 8 + (col >> 5);
                Ht[(kt * 32 + m) * 32 + (chunk ^ (m & 3)) * 8 + (col & 7)] =
                    __float2bfloat16(acc[r][c][i] + bv);
            }
        }
    }
    __syncthreads();

    // ---- phase 2: M=32 from Ht, B-only PIPE ----
    auto stage2 = [&](int ke, int buf) {
        char* Bsm = smem + buf * STAGE + ASZ;
        #pragma unroll
        for (int i = 0; i < 2; ++i) {
            int s = i * 512 + t;
            int col = s >> 2;
            int kcd2 = (s & 3) ^ ((col >> 2) & 3);
            async_load16(BT + (size_t)col * 1024 + ke + kcd2 * 8, Bsm + i * 8192 + w * 1024);
        }
    };

    f32x4 acc2[4] = {};   // 4 col-frags for this wave (rows: rg must be 0)
    stage2(0, 0);
    stage2(32, 1);
    for (int k0 = 0; k0 < 32; ++k0) {
        if (k0 + 1 < 32)
            asm volatile("s_waitcnt vmcnt(2)\n\ts_barrier" ::: "memory");
        else
            asm volatile("s_waitcnt vmcnt(0)\n\ts_barrier" ::: "memory");
        if (k0 + 2 < 32) stage2((k0 + 2) * 32, (k0 + 2) % 3);
        const bf16* Bs16 = (const bf16*)(smem + (k0 % 3) * STAGE + ASZ);
        int m = (rg * 64 + mi) & 31;                 // valid rows 0..31 (rg0, r=0..1 span 0..31)
        bf16x8 a = *(const bf16x8*)(Ht + (k0 * 32 + m) * 32 + (q ^ (m & 3)) * 8);
        #pragma unroll
        for (int c = 0; c < 4; ++c) {
            int col = cg * 64 + c * 16 + mi;
            int slot = col * 4 + (q ^ ((col >> 2) & 3));
            bf16x8 b = *(const bf16x8*)(Bs16 + slot * 8);
            acc2[c] = __builtin_amdgcn_mfma_f32_16x16x32_bf16(a, b, acc2[c], 0, 0, 0);
        }
    }
    // phase-2 epilogue: rows 0..15 (m=mi when rg==0 covers A rows mi; C rows = mi? no:
    // C/D layout: row = q*4+i, col = mi-based. Output rows 0..31 live in rg==0 frags.
    if (rg == 0) {
        #pragma unroll
        for (int c = 0; c < 4; ++c) {
            int col = cg * 64 + c * 16 + mi;
            float bv = b4[col];
            #pragma unroll
            for (int i = 0; i < 4; ++i) {
                int rowL = q * 4 + i;                // 0..15 from this frag
                out[(size_t)(blockIdx.x * 32 + rowL) * 256 + col] = acc2[c][i] + bv;
            }
        }
    } else {
        // rg==1 computed A rows (64+mi)&31 = 32+mi-32.. -> rows 16..31? No:
        // (64+mi)&31 = mi -> duplicate of rg0? Avoid double-write: rg1 handles rows 16..31
        // only if mapping differs; with &31 it duplicates rows 0..15 -> discard.
    }
    // rows 16..31: computed by rg==0 with mi 0..15? No — A-row m = mi covers 0..15 only.
    // Handle 16..31 via rg==1 with m = 16 + mi:
    if (rg == 1) {
        // recompute? No — rg1's m = (64+mi)&31 = mi.. WRONG rows. Fixed below in launch:
    }
}

extern "C" void kernel_launch(void* const* d_in, const int* in_sizes, int n_in,
                              void* d_out, int out_size, void* d_ws, size_t ws_size,
                              hipStream_t stream) {
    const int*   ids = (const int*)d_in[0];
    const float* emb = (const float*)d_in[1];
    const float* W1  = (const float*)d_in[2];
    const float* b1  = (const float*)d_in[3];
    const float* W2  = (const float*)d_in[4];
    const float* b2  = (const float*)d_in[5];
    (void)in_sizes; (void)n_in; (void)out_size; (void)ws_size;

    char* ws = (char*)d_ws;
    size_t off = 0;
    float* zbuf = (float*)(ws + off); off += 1024;
    float* b4   = (float*)(ws + off); off += 1024;
    bf16* w1t = (bf16*)(ws + off); off += (size_t)256 * KP1 * 2;     // 160 KB
    bf16* w2t = (bf16*)(ws + off); off += (size_t)256 * 512 * 2;     // 256 KB
    bf16* w2b = (bf16*)(ws + off); off += (size_t)512 * 256 * 2;     // 256 KB
    bf16* w4t = (bf16*)(ws + off); off += (size_t)256 * 1024 * 2;    // 512 KB
    bf16* proj = (bf16*)(ws + off); off += (size_t)MP * 256 * 2;     // 25.8 MB
    bf16* h  = (bf16*)(ws + off); off += (size_t)65536 * 256 * 2;    // 33.5 MB
    bf16* t1 = (bf16*)(ws + off); off += (size_t)16384 * 256 * 2;    // 8.4 MB
    bf16* t2 = (bf16*)(ws + off); off += (size_t)4096 * 256 * 2;     // 2.1 MB
    (void)off;

    // 1) weight casts/transposes + b4 + zeros
    prep_w<<<1345, 256, 0, stream>>>(W1, W2, b2, w1t, w2t, w2b, b4, zbuf);

    // 2) W4T products
    gemm128<3, false><<<dim3(2, 2, 4), 256, 0, stream>>>(
        w2t, w2b, nullptr, w4t, 256, 256, 512, 256, 1024);

    // 3) projected embedding table: proj = emb @ W1 + b1
    gemm512<2, false, false><<<MP / 128, 512, 0, stream>>>(
        emb, nullptr, w1t, b1, proj, KP1, zbuf);

    // 4) main: leaves + levels 0-1 fused, full-N + PIPE (proven ~3x win R7)
    gemm512<1, true, false><<<512, 512, 0, stream>>>(
        proj, ids, w4t, b4, h, 1024, nullptr);

    // 5) tail levels, batched full-M (PIPE):
    gemm512<0, true, false><<<128, 512, 0, stream>>>(h,  nullptr, w4t, b4, t1, 1024, nullptr);
    gemm512<0, true, false><<<32,  512, 0, stream>>>(t1, nullptr, w4t, b4, t2, 1024, nullptr);
    gemm512<0, true, false><<<8,   512, 0, stream>>>(t2, nullptr, w4t, b4, t1, 1024, nullptr); // t1 reused: t3 [1024x256]
    gemm512<0, true, true><<<2,    512, 0, stream>>>(t1, nullptr, w4t, b4, d_out, 1024, nullptr);
}

// Round 10
// 239.858 us; speedup vs baseline: 1.1174x; 1.1174x over previous
//
#include <hip/hip_runtime.h>
#include <hip/hip_bf16.h>
#include <stdint.h>

#define VOCAB 50257
#define WD 300
#define KP1 320              // word dim padded to mult of 32
#define MP 50432             // vocab rows padded: 394*128

using bf16 = __hip_bfloat16;
typedef __attribute__((ext_vector_type(4))) float f32x4;
typedef __attribute__((ext_vector_type(8))) short bf16x8;

// async global->LDS, 16B per lane; LDS dest = wave-uniform base + lane*16
__device__ __forceinline__ void async_load16(const void* g, void* l) {
    __builtin_amdgcn_global_load_lds(
        (const __attribute__((address_space(1))) uint32_t*)(uintptr_t)g,
        (__attribute__((address_space(3))) uint32_t*)l, 16, 0, 0);
}

// ---------- prep: w1t = W1^T bf16 [256x320]; w2t = W2^T bf16 [256x512];
//                  w2b = W2 cast bf16 [512x256]; b4 = b2@(A+B)+b2; zbuf zeros(256)
__global__ void prep_w(const float* __restrict__ W1, const float* __restrict__ W2,
                       const float* __restrict__ b2,
                       bf16* __restrict__ w1t, bf16* __restrict__ w2t,
                       bf16* __restrict__ w2b, float* __restrict__ b4,
                       float* __restrict__ zbuf) {
    if (blockIdx.x == 1344) {           // bias block: b4 = b2@(A+B) + b2
        __shared__ float b2s[256];
        int n = threadIdx.x;
        b2s[n] = b2[n];
        zbuf[n] = 0.0f;                 // 256 zeros (W4T bias + fp32 pad source)
        __syncthreads();
        float acc = b2s[n];
        #pragma unroll 8
        for (int k = 0; k < 256; ++k)
            acc += b2s[k] * (W2[k * 256 + n] + W2[(k + 256) * 256 + n]);
        b4[n] = acc;
        return;
    }
    int idx = blockIdx.x * 256 + threadIdx.x;
    if (idx < 256 * KP1) {                              // w1t
        int n = idx / KP1;
        int k = idx - n * KP1;
        w1t[idx] = __float2bfloat16(k < WD ? W1[k * 256 + n] : 0.0f);
    } else if (idx < 256 * KP1 + 131072) {              // w2t
        int j = idx - 256 * KP1;
        int n = j >> 9, k = j & 511;
        w2t[j] = __float2bfloat16(W2[k * 256 + n]);
    } else {                                            // w2b: plain cast
        int j = idx - 256 * KP1 - 131072;
        w2b[j] = __float2bfloat16(W2[j]);
    }
}

// ---------- unified 128-row x 256-col tile (8 waves: 2 rg x 4 cgr) -----------
// AMODE 0: A bf16, row stride As elems; 3-stage PIPE (verified R8)
// AMODE 1: A row r = concat4(proj[ids4[m0+r]]), K = 1024; 3-stage PIPE (R8)
// AMODE 2: A fp32 rows stride WD (emb, clamped); single-stage 2-barrier (R6/R8)
template <int AMODE, bool OUT_F32>
__device__ __forceinline__ void tile_gemm(
    char* smem, const void* Av, const int* ids,
    const bf16* BT, int Bstr, const float* bias,
    void* C, int Cs, int coff, int K, int As, int m0,
    const float* zbuf)
{
    constexpr int ASZ = (AMODE == 2) ? 16384 : 8192;
    constexpr int BSZ = 16384, STAGE = ASZ + BSZ;

    const int t = threadIdx.x, w = t >> 6, lane = t & 63;
    const int rg = w >> 2, cgr = w & 3, mi = lane & 15, q = lane >> 4;
    const bf16* Ab = (const bf16*)Av;

    int4 idq = {0, 0, 0, 0};
    if constexpr (AMODE == 1) idq = ((const int4*)ids)[m0 + (t >> 2)];

    auto stage = [&](int ke, int buf) {
        char* Asm = smem + buf * STAGE;
        char* Bsm = Asm + ASZ;
        if constexpr (AMODE == 2) {
            const float* A32 = (const float*)Av;
            #pragma unroll
            for (int i = 0; i < 2; ++i) {               // 1024 fp32x4 chunks
                int s = i * 512 + t;
                int row = s >> 3;
                int kcd = (s & 7) ^ (row & 7);
                int k = ke + kcd * 4;
                int grow = m0 + row; if (grow >= VOCAB) grow = VOCAB - 1;
                const float* g = (k <= 296) ? (A32 + (size_t)grow * WD + k) : zbuf;
                async_load16(g, Asm + i * 8192 + w * 1024);
            }
        } else {
            int row = t >> 2;                           // 512 bf16x8 chunks, 1/thread
            int kcd = (t & 3) ^ ((row >> 2) & 3);
            const bf16* g;
            if constexpr (AMODE == 1) {
                int sel = ke >> 8;                      // leaf slot, wave-uniform
                int id = (sel & 2) ? ((sel & 1) ? idq.w : idq.z)
                                   : ((sel & 1) ? idq.y : idq.x);
                g = Ab + (size_t)id * 256 + (ke & 255) + kcd * 8;
            } else {
                g = Ab + (size_t)(m0 + row) * As + ke + kcd * 8;
            }
            async_load16(g, Asm + w * 1024);
        }
        #pragma unroll
        for (int i = 0; i < 2; ++i) {                   // B: 1024 chunks, 2/thread
            int s = i * 512 + t;
            int col = s >> 2;
            int kcd = (s & 3) ^ ((col >> 2) & 3);
            async_load16(BT + (size_t)col * Bstr + ke + kcd * 8,
                         Bsm + i * 8192 + w * 1024);
        }
    };

    f32x4 acc[4][4] = {};

    auto compute = [&](int buf) {
        const char* Asm = smem + buf * STAGE;
        const bf16* Bs16 = (const bf16*)(Asm + ASZ);
        bf16x8 af[4], bfr[4];
        if constexpr (AMODE == 2) {
            const float* As32 = (const float*)Asm;
            #pragma unroll
            for (int r = 0; r < 4; ++r) {
                int row = rg * 64 + r * 16 + mi;
                int sl = row * 8 + ((2 * q) ^ (row & 7));
                f32x4 lo = *(const f32x4*)(As32 + sl * 4);
                f32x4 hi = *(const f32x4*)(As32 + (sl ^ 1) * 4);
                union { bf16x8 v; bf16 hh[8]; } u;
                #pragma unroll
                for (int j = 0; j < 4; ++j) u.hh[j] = __float2bfloat16(lo[j]);
                #pragma unroll
                for (int j = 0; j < 4; ++j) u.hh[4 + j] = __float2bfloat16(hi[j]);
                af[r] = u.v;
            }
        } else {
            const bf16* As16 = (const bf16*)Asm;
            #pragma unroll
            for (int r = 0; r < 4; ++r) {
                int row = rg * 64 + r * 16 + mi;
                int slot = row * 4 + (q ^ ((row >> 2) & 3));
                af[r] = *(const bf16x8*)(As16 + slot * 8);
            }
        }
        #pragma unroll
        for (int c = 0; c < 4; ++c) {
            int col = cgr * 64 + c * 16 + mi;
            int slot = col * 4 + (q ^ ((col >> 2) & 3));
            bfr[c] = *(const bf16x8*)(Bs16 + slot * 8);
        }
        #pragma unroll
        for (int r = 0; r < 4; ++r)
            #pragma unroll
            for (int c = 0; c < 4; ++c)
                acc[r][c] = __builtin_amdgcn_mfma_f32_16x16x32_bf16(af[r], bfr[c], acc[r][c], 0, 0, 0);
    };

    const int S = K >> 5;
    if constexpr (AMODE == 2) {
        for (int k0 = 0; k0 < S; ++k0) {                // 2-barrier (verified)
            stage(k0 * 32, 0);
            __syncthreads();
            compute(0);
            __syncthreads();
        }
    } else {
        stage(0, 0);                                     // 3-stage PIPE (verified)
        if (S > 1) stage(32, 1);
        for (int k0 = 0; k0 < S; ++k0) {
            if (k0 + 1 < S)
                asm volatile("s_waitcnt vmcnt(3)\n\ts_barrier" ::: "memory");
            else
                asm volatile("s_waitcnt vmcnt(0)\n\ts_barrier" ::: "memory");
            if (k0 + 2 < S) stage((k0 + 2) * 32, (k0 + 2) % 3);
            compute(k0 % 3);
        }
    }

    // epilogue: C/D layout col = lane&15, row = (lane>>4)*4 + i
    #pragma unroll
    for (int r = 0; r < 4; ++r) {
        int rowb = m0 + rg * 64 + r * 16 + q * 4;
        #pragma unroll
        for (int c = 0; c < 4; ++c) {
            int col = cgr * 64 + c * 16 + mi;
            float bv = bias[col];
            #pragma unroll
            for (int i = 0; i < 4; ++i) {
                float v = acc[r][c][i] + bv;
                size_t o = (size_t)(rowb + i) * Cs + coff + col;
                if (OUT_F32) ((float*)C)[o] = v;
                else         ((bf16*)C)[o] = __float2bfloat16(v);
            }
        }
    }
}

// ---------- D2: W4T (blocks 0..7) || proj (blocks 8..401) --------------------
__global__ __launch_bounds__(512)
void combo(const float* __restrict__ emb, const bf16* __restrict__ w1t,
           const float* __restrict__ b1, const bf16* __restrict__ w2t,
           const bf16* __restrict__ w2b, bf16* __restrict__ w4t,
           bf16* __restrict__ proj, const float* __restrict__ zbuf) {
    __shared__ char smem[73728];
    int blk = blockIdx.x;
    if (blk < 8) {
        int j = blk >> 1, s = blk & 1;
        tile_gemm<0, false>(smem, w2t + 256 * (j >> 1), nullptr,
                            w2b + 65536 * (j & 1), 256, zbuf,
                            w4t, 1024, 256 * j, 256, 512, s * 128, nullptr);
    } else {
        tile_gemm<2, false>(smem, emb, nullptr, w1t, KP1, b1,
                            proj, 256, 0, KP1, WD, (blk - 8) * 128, zbuf);
    }
}

// ---------- D3: main — h = concat4(proj[ids4]) @ W4 + b4 ---------------------
__global__ __launch_bounds__(512)
void mainK(const bf16* __restrict__ proj, const int* __restrict__ ids,
           const bf16* __restrict__ w4t, const float* __restrict__ b4,
           bf16* __restrict__ h) {
    __shared__ char smem[73728];
    tile_gemm<1, false>(smem, proj, ids, w4t, 1024, b4,
                        h, 256, 0, 1024, 256, blockIdx.x * 128, nullptr);
}

// ---------- D4: t1 = view(h,[16384x1024]) @ W4 + b4 --------------------------
__global__ __launch_bounds__(512)
void t1K(const bf16* __restrict__ h, const bf16* __restrict__ w4t,
         const float* __restrict__ b4, bf16* __restrict__ t1) {
    __shared__ char smem[73728];
    tile_gemm<0, false>(smem, h, nullptr, w4t, 1024, b4,
                        t1, 256, 0, 1024, 1024, blockIdx.x * 128, nullptr);
}

// ---------- D5: tail3 — t2 + t3 + roots in one dispatch (32 blocks) ----------
// Block b: t2 rows [128b,128b+128) via standard PIPE tile -> LDS Ht (swizzled);
// t3 rows [32b,32b+32) from Ht (A) + B-only PIPE -> LDS Ht2; roots [8b,8b+8)
// from Ht2 + B-only PIPE -> fp32 out. No un-pipelined global loads on MFMA path.
__global__ __launch_bounds__(512)
void tail3(const bf16* __restrict__ t1, const bf16* __restrict__ w4t,
           const float* __restrict__ b4, float* __restrict__ out) {
    constexpr int ASZ = 8192, BSZ = 16384, STAGE = ASZ + BSZ;
    __shared__ char smem[3 * STAGE];   // 72 KB
    __shared__ bf16 Ht[128 * 256];     // 64 KB
    __shared__ bf16 Ht2[32 * 256];     // 16 KB   (total 152 KB < 160)

    const int t = threadIdx.x, w = t >> 6, lane = t & 63;
    const int rg = w >> 2, cgr = w & 3, mi = lane & 15, q = lane >> 4;
    const int b = blockIdx.x;
    const int m0 = b * 128;

    auto stageA = [&](int ke, int buf) {
        char* Asm = smem + buf * STAGE;
        char* Bsm = Asm + ASZ;
        int row = t >> 2;
        int kcd = (t & 3) ^ ((row >> 2) & 3);
        async_load16(t1 + (size_t)(m0 + row) * 1024 + ke + kcd * 8, Asm + w * 1024);
        #pragma unroll
        for (int i = 0; i < 2; ++i) {
            int s = i * 512 + t;
            int col = s >> 2;
            int kcd2 = (s & 3) ^ ((col >> 2) & 3);
            async_load16(w4t + (size_t)col * 1024 + ke + kcd2 * 8,
                         Bsm + i * 8192 + w * 1024);
        }
    };
    auto stageB = [&](int ke, int buf) {               // B-only
        char* Bsm = smem + buf * STAGE + ASZ;
        #pragma unroll
        for (int i = 0; i < 2; ++i) {
            int s = i * 512 + t;
            int col = s >> 2;
            int kcd2 = (s & 3) ^ ((col >> 2) & 3);
            async_load16(w4t + (size_t)col * 1024 + ke + kcd2 * 8,
                         Bsm + i * 8192 + w * 1024);
        }
    };

    // ---- phase A: t2 tile [128 x 256] -> Ht ----
    {
        f32x4 acc[4][4] = {};
        stageA(0, 0); stageA(32, 1);
        for (int k0 = 0; k0 < 32; ++k0) {
            if (k0 + 1 < 32)
                asm volatile("s_waitcnt vmcnt(3)\n\ts_barrier" ::: "memory");
            else
                asm volatile("s_waitcnt vmcnt(0)\n\ts_barrier" ::: "memory");
            if (k0 + 2 < 32) stageA((k0 + 2) * 32, (k0 + 2) % 3);
            const bf16* As16 = (const bf16*)(smem + (k0 % 3) * STAGE);
            const bf16* Bs16 = (const bf16*)(smem + (k0 % 3) * STAGE + ASZ);
            bf16x8 af[4], bfr[4];
            #pragma unroll
            for (int r = 0; r < 4; ++r) {
                int row = rg * 64 + r * 16 + mi;
                int slot = row * 4 + (q ^ ((row >> 2) & 3));
                af[r] = *(const bf16x8*)(As16 + slot * 8);
            }
            #pragma unroll
            for (int c = 0; c < 4; ++c) {
                int col = cgr * 64 + c * 16 + mi;
                int slot = col * 4 + (q ^ ((col >> 2) & 3));
                bfr[c] = *(const bf16x8*)(Bs16 + slot * 8);
            }
            #pragma unroll
            for (int r = 0; r < 4; ++r)
                #pragma unroll
                for (int c = 0; c < 4; ++c)
                    acc[r][c] = __builtin_amdgcn_mfma_f32_16x16x32_bf16(af[r], bfr[c], acc[r][c], 0, 0, 0);
        }
        // epilogue -> Ht, slot(row,col) = (row*32 + ((col>>3) ^ (row&31)))*8 + (col&7)
        #pragma unroll
        for (int r = 0; r < 4; ++r) {
            int rowb = rg * 64 + r * 16 + q * 4;
            #pragma unroll
            for (int c = 0; c < 4; ++c) {
                int col = cgr * 64 + c * 16 + mi;
                float bv = b4[col];
                int chunk = col >> 3;
                #pragma unroll
                for (int i = 0; i < 4; ++i) {
                    int row = rowb + i;
                    Ht[(row * 32 + (chunk ^ (row & 31))) * 8 + (col & 7)] =
                        __float2bfloat16(acc[r][c][i] + bv);
                }
            }
        }
    }
    __syncthreads();

    // ---- phase B: t3-local [32 x 256] = view(Ht,[32x1024]) @ W4 + b4 -> Ht2 ----
    {
        f32x4 acc[4] = {};
        stageB(0, 0); stageB(32, 1);
        for (int k0i = 0; k0i < 32; ++k0i) {
            int k0 = k0i * 32;
            if (k0i + 1 < 32)
                asm volatile("s_waitcnt vmcnt(2)\n\ts_barrier" ::: "memory");
            else
                asm volatile("s_waitcnt vmcnt(0)\n\ts_barrier" ::: "memory");
            if (k0i + 2 < 32) stageB((k0i + 2) * 32, (k0i + 2) % 3);
            const bf16* Bs16 = (const bf16*)(smem + (k0i % 3) * STAGE + ASZ);
            int n = rg * 16 + mi;                       // A row 0..31
            int sel = k0 >> 8;
            int r2 = 4 * n + sel;                       // Ht row 0..127
            int kc = ((k0 & 255) >> 3) + q;
            bf16x8 a = *(const bf16x8*)(Ht + (r2 * 32 + (kc ^ (r2 & 31))) * 8);
            #pragma unroll
            for (int c = 0; c < 4; ++c) {
                int col = cgr * 64 + c * 16 + mi;
                int slot = col * 4 + (q ^ ((col >> 2) & 3));
                bf16x8 bb = *(const bf16x8*)(Bs16 + slot * 8);
                acc[c] = __builtin_amdgcn_mfma_f32_16x16x32_bf16(a, bb, acc[c], 0, 0, 0);
            }
        }
        __syncthreads();
        #pragma unroll
        for (int c = 0; c < 4; ++c) {
            int col = cgr * 64 + c * 16 + mi;
            float bv = b4[col];
            int chunk = col >> 3;
            #pragma unroll
            for (int i = 0; i < 4; ++i) {
                int row = rg * 16 + q * 4 + i;          // 0..31
                Ht2[(row * 32 + (chunk ^ (row & 31))) * 8 + (col & 7)] =
                    __float2bfloat16(acc[c][i] + bv);
            }
        }
    }
    __syncthreads();

    // ---- phase C: roots [8 x 256] = view(Ht2,[8x1024]) @ W4 + b4 -> out ----
    {
        f32x4 acc[4] = {};
        stageB(0, 0); stageB(32, 1);
        for (int k0i = 0; k0i < 32; ++k0i) {
            int k0 = k0i * 32;
            if (k0i + 1 < 32)
                asm volatile("s_waitcnt vmcnt(2)\n\ts_barrier" ::: "memory");
            else
                asm volatile("s_waitcnt vmcnt(0)\n\ts_barrier" ::: "memory");
            if (k0i + 2 < 32) stageB((k0i + 2) * 32, (k0i + 2) % 3);
            const bf16* Bs16 = (const bf16*)(smem + (k0i % 3) * STAGE + ASZ);
            int sel = k0 >> 8;
            int r3 = (4 * mi + sel) & 31;               // valid for mi<8; rest garbage
            int kc = ((k0 & 255) >> 3) + q;
            bf16x8 a = *(const bf16x8*)(Ht2 + (r3 * 32 + (kc ^ (r3 & 31))) * 8);
            #pragma unroll
            for (int c = 0; c < 4; ++c) {
                int col = cgr * 64 + c * 16 + mi;
                int slot = col * 4 + (q ^ ((col >> 2) & 3));
                bf16x8 bb = *(const bf16x8*)(Bs16 + slot * 8);
                acc[c] = __builtin_amdgcn_mfma_f32_16x16x32_bf16(a, bb, acc[c], 0, 0, 0);
            }
        }
        if (rg == 0 && q < 2) {                         // rows 0..7 valid; rg1 duplicates
            #pragma unroll
            for (int c = 0; c < 4; ++c) {
                int col = cgr * 64 + c * 16 + mi;
                float bv = b4[col];
                #pragma unroll
                for (int i = 0; i < 4; ++i)
                    out[(size_t)(b * 8 + q * 4 + i) * 256 + col] = acc[c][i] + bv;
            }
        }
    }
}

extern "C" void kernel_launch(void* const* d_in, const int* in_sizes, int n_in,
                              void* d_out, int out_size, void* d_ws, size_t ws_size,
                              hipStream_t stream) {
    const int*   ids = (const int*)d_in[0];
    const float* emb = (const float*)d_in[1];
    const float* W1  = (const float*)d_in[2];
    const float* b1  = (const float*)d_in[3];
    const float* W2  = (const float*)d_in[4];
    const float* b2  = (const float*)d_in[5];
    (void)in_sizes; (void)n_in; (void)out_size; (void)ws_size;

    char* ws = (char*)d_ws;
    size_t off = 0;
    float* zbuf = (float*)(ws + off); off += 1024;
    float* b4   = (float*)(ws + off); off += 1024;
    bf16* w1t = (bf16*)(ws + off); off += (size_t)256 * KP1 * 2;     // 160 KB
    bf16* w2t = (bf16*)(ws + off); off += (size_t)256 * 512 * 2;     // 256 KB
    bf16* w2b = (bf16*)(ws + off); off += (size_t)512 * 256 * 2;     // 256 KB
    bf16* w4t = (bf16*)(ws + off); off += (size_t)256 * 1024 * 2;    // 512 KB
    bf16* proj = (bf16*)(ws + off); off += (size_t)MP * 256 * 2;     // 25.8 MB
    bf16* h  = (bf16*)(ws + off); off += (size_t)65536 * 256 * 2;    // 33.5 MB
    bf16* t1 = (bf16*)(ws + off); off += (size_t)16384 * 256 * 2;    // 8.4 MB
    (void)off;

    // D1: weight casts/transposes + b4 + zeros
    prep_w<<<1345, 256, 0, stream>>>(W1, W2, b2, w1t, w2t, w2b, b4, zbuf);

    // D2: W4T products (blocks 0..7) || proj = emb@W1+b1 (blocks 8..401)
    combo<<<402, 512, 0, stream>>>(emb, w1t, b1, w2t, w2b, w4t, proj, zbuf);

    // D3: main — leaves + levels 0-1 fused (PIPE)
    mainK<<<512, 512, 0, stream>>>(proj, ids, w4t, b4, h);

    // D4: t1 = level 2-3 (view [16384x1024], PIPE)
    t1K<<<128, 512, 0, stream>>>(h, w4t, b4, t1);

    // D5: levels 4-9 block-local: t2 (PIPE tile) + t3 + roots, one dispatch
    tail3<<<32, 512, 0, stream>>>(t1, w4t, b4, (float*)d_out);
}